// Round 2
// baseline (310.039 us; speedup 1.0000x reference)
//
#include <hip/hip_runtime.h>

// SPN left-to-right propagation, barrier-free formulation.
//
// h[:, :, i, t] = (1-g1-g2-g3)*x[...,i,t]
//              + g1*h[...,i-1,t-1] + g2*h[...,i,t-1] + g3*h[...,i+1,t-1]
// Gates normalized elementwise: if |G1|+|G2|+|G3| >= 1, divide by the sum.
//
// Mapping: one WAVE per (b,c) plane (grid=256 blocks x 64 threads).
// Lane l owns 4 contiguous rows 4l..4l+3 (h0..h3 in registers). The
// tridiagonal exchange needs only 2 cross-lane ops per step:
//   up(row 4l)   = lane l-1's h3  -> __shfl_up(h3,1)
//   dn(row 4l+3) = lane l+1's h0  -> __shfl_down(h0,1)
// No LDS, no s_barrier, no inter-wave lockstep (round 1 was sync-bound at
// ~940 cy/step vs ~210 cy/step memory floor).
//
// Memory: lane-private rows -> divergent but fully line-utilized float4
// loads (same pattern as round 1, which showed ideal FETCH/WRITE). Two
// chunks (CH=4 cols) of register prefetch = 32KB/wave in flight, enough to
// cover ~900cy HBM latency. Buffers are statically double-buffered (named
// A/B, manual 2x loop body) so nothing is runtime-indexed into scratch.

#define HH 256
#define WW 256
#define CH 4              // columns per chunk = one float4 per row per array
#define NCH (WW / CH)     // 64 chunks

#define ELEM(v, k) ((k) == 0 ? (v).x : ((k) == 1 ? (v).y : ((k) == 2 ? (v).z : (v).w)))
#define SETEL(v, k, val)                                                     \
    do {                                                                     \
        if ((k) == 0) (v).x = (val);                                         \
        else if ((k) == 1) (v).y = (val);                                    \
        else if ((k) == 2) (v).z = (val);                                    \
        else (v).w = (val);                                                  \
    } while (0)

extern "C" __global__ void __launch_bounds__(64, 1)
spn_lr_wave(const float* __restrict__ xg, const float* __restrict__ g1g,
            const float* __restrict__ g2g, const float* __restrict__ g3g,
            float* __restrict__ outg) {
    const int lane = threadIdx.x;  // 0..63
    // float4 indices: plane base + row*(WW/4)
    const size_t pbase = (size_t)blockIdx.x * (size_t)(HH * (WW / 4));
    const size_t rb0 = pbase + (size_t)(4 * lane + 0) * (WW / 4);
    const size_t rb1 = pbase + (size_t)(4 * lane + 1) * (WW / 4);
    const size_t rb2 = pbase + (size_t)(4 * lane + 2) * (WW / 4);
    const size_t rb3 = pbase + (size_t)(4 * lane + 3) * (WW / 4);

    const float4* px = reinterpret_cast<const float4*>(xg);
    const float4* p1 = reinterpret_cast<const float4*>(g1g);
    const float4* p2 = reinterpret_cast<const float4*>(g2g);
    const float4* p3 = reinterpret_cast<const float4*>(g3g);
    float4* po = reinterpret_cast<float4*>(outg);

    // Static double buffers (A = even chunks, B = odd chunks). [row] only.
    float4 bxA[4], b1A[4], b2A[4], b3A[4];
    float4 bxB[4], b1B[4], b2B[4], b3B[4];

    // Prefetch chunk 0 -> A, chunk 1 -> B.
    {
        bxA[0] = px[rb0 + 0]; bxA[1] = px[rb1 + 0]; bxA[2] = px[rb2 + 0]; bxA[3] = px[rb3 + 0];
        b1A[0] = p1[rb0 + 0]; b1A[1] = p1[rb1 + 0]; b1A[2] = p1[rb2 + 0]; b1A[3] = p1[rb3 + 0];
        b2A[0] = p2[rb0 + 0]; b2A[1] = p2[rb1 + 0]; b2A[2] = p2[rb2 + 0]; b2A[3] = p2[rb3 + 0];
        b3A[0] = p3[rb0 + 0]; b3A[1] = p3[rb1 + 0]; b3A[2] = p3[rb2 + 0]; b3A[3] = p3[rb3 + 0];
        bxB[0] = px[rb0 + 1]; bxB[1] = px[rb1 + 1]; bxB[2] = px[rb2 + 1]; bxB[3] = px[rb3 + 1];
        b1B[0] = p1[rb0 + 1]; b1B[1] = p1[rb1 + 1]; b1B[2] = p1[rb2 + 1]; b1B[3] = p1[rb3 + 1];
        b2B[0] = p2[rb0 + 1]; b2B[1] = p2[rb1 + 1]; b2B[2] = p2[rb2 + 1]; b2B[3] = p2[rb3 + 1];
        b3B[0] = p3[rb0 + 1]; b3B[1] = p3[rb1 + 1]; b3B[2] = p3[rb2 + 1]; b3B[3] = p3[rb3 + 1];
    }

    float h0 = 0.0f, h1 = 0.0f, h2 = 0.0f, h3 = 0.0f;

    // One-chunk body as a macro over the named buffer set (static indexing).
#define DO_CHUNK(TC, BX, B1, B2, B3)                                          \
    do {                                                                      \
        const int tc_ = (TC);                                                 \
        /* 1) normalize current chunk into scalar regs (consumes buffers) */  \
        float xs[4][4], aa[4][4], c1[4][4], c2[4][4], c3[4][4];               \
        _Pragma("unroll") for (int q = 0; q < 4; ++q) {                       \
            float4 vx = BX[q], v1 = B1[q], v2 = B2[q], v3 = B3[q];            \
            _Pragma("unroll") for (int k = 0; k < 4; ++k) {                   \
                float A1 = ELEM(v1, k), A2 = ELEM(v2, k), A3 = ELEM(v3, k);   \
                float sa = fabsf(A1) + fabsf(A2) + fabsf(A3);                 \
                sa = (sa == 0.0f) ? 1e-6f : sa;                               \
                const float inv = 1.0f / sa;                                  \
                const bool m = (sa >= 1.0f);                                  \
                const float Q1 = m ? A1 * inv : A1;                           \
                const float Q2 = m ? A2 * inv : A2;                           \
                const float Q3 = m ? A3 * inv : A3;                           \
                xs[q][k] = ELEM(vx, k);                                       \
                c1[q][k] = Q1; c2[q][k] = Q2; c3[q][k] = Q3;                  \
                aa[q][k] = 1.0f - Q1 - Q2 - Q3;                               \
            }                                                                 \
        }                                                                     \
        /* 2) prefetch chunk tc+2 into the same (now free) buffers */         \
        if (tc_ + 2 < NCH) {                                                  \
            const int o = tc_ + 2;                                            \
            BX[0] = px[rb0 + o]; BX[1] = px[rb1 + o];                         \
            BX[2] = px[rb2 + o]; BX[3] = px[rb3 + o];                         \
            B1[0] = p1[rb0 + o]; B1[1] = p1[rb1 + o];                         \
            B1[2] = p1[rb2 + o]; B1[3] = p1[rb3 + o];                         \
            B2[0] = p2[rb0 + o]; B2[1] = p2[rb1 + o];                         \
            B2[2] = p2[rb2 + o]; B2[3] = p2[rb3 + o];                         \
            B3[0] = p3[rb0 + o]; B3[1] = p3[rb1 + o];                         \
            B3[2] = p3[rb2 + o]; B3[3] = p3[rb3 + o];                         \
        }                                                                     \
        /* 3) 4 recurrence steps, shfl-only exchange */                       \
        float4 o0, o1, o2, o3;                                                \
        _Pragma("unroll") for (int k = 0; k < 4; ++k) {                       \
            float up = __shfl_up(h3, 1);                                      \
            float dn = __shfl_down(h0, 1);                                    \
            up = (lane == 0) ? 0.0f : up;                                     \
            dn = (lane == 63) ? 0.0f : dn;                                    \
            const float t0 = aa[0][k] * xs[0][k] + c1[0][k] * up +            \
                             c2[0][k] * h0 + c3[0][k] * h1;                   \
            const float t1 = aa[1][k] * xs[1][k] + c1[1][k] * h0 +            \
                             c2[1][k] * h1 + c3[1][k] * h2;                   \
            const float t2 = aa[2][k] * xs[2][k] + c1[2][k] * h1 +            \
                             c2[2][k] * h2 + c3[2][k] * h3;                   \
            const float t3 = aa[3][k] * xs[3][k] + c1[3][k] * h2 +            \
                             c2[3][k] * h3 + c3[3][k] * dn;                   \
            h0 = t0; h1 = t1; h2 = t2; h3 = t3;                               \
            SETEL(o0, k, t0); SETEL(o1, k, t1);                               \
            SETEL(o2, k, t2); SETEL(o3, k, t3);                               \
        }                                                                     \
        /* 4) store the 4 rows' float4 for this chunk */                      \
        po[rb0 + tc_] = o0; po[rb1 + tc_] = o1;                               \
        po[rb2 + tc_] = o2; po[rb3 + tc_] = o3;                               \
    } while (0)

#pragma unroll 1
    for (int t = 0; t < NCH; t += 2) {
        DO_CHUNK(t, bxA, b1A, b2A, b3A);
        DO_CHUNK(t + 1, bxB, b1B, b2B, b3B);
    }
#undef DO_CHUNK
}

extern "C" void kernel_launch(void* const* d_in, const int* in_sizes, int n_in,
                              void* d_out, int out_size, void* d_ws, size_t ws_size,
                              hipStream_t stream) {
    const float* x  = (const float*)d_in[0];
    const float* G1 = (const float*)d_in[1];
    const float* G2 = (const float*)d_in[2];
    const float* G3 = (const float*)d_in[3];
    float* out = (float*)d_out;

    const int nplanes = in_sizes[0] / (HH * WW);  // B*C = 256
    spn_lr_wave<<<dim3(nplanes), dim3(64), 0, stream>>>(x, G1, G2, G3, out);
}

// Round 3
// 232.611 us; speedup vs baseline: 1.3329x; 1.3329x over previous
//
#include <hip/hip_runtime.h>

// SPN left-to-right propagation, single-wave-per-plane, barrier-free, with
// global_load_lds full-line staging through a 4-slot LDS ring.
//
// h[:,:,i,t] = (1-g1-g2-g3)*x[...,i,t] + g1*h[i-1,t-1] + g2*h[i,t-1] + g3*h[i+1,t-1]
// Gates: if |G1|+|G2|+|G3| >= 1 divide by the sum (eps branch is dead code:
// sa==0 -> sa<1 -> keep raw).
//
// Mapping: grid=256 (one plane per block), block=64 (ONE wave). Lane l owns
// rows 4l..4l+3; tridiagonal exchange = 2 shfl per step. No s_barrier at all.
//
// Memory (fix for round 2's 4x L2-thrash overfetch): per f4-col-group G
// (4 cols), 16 global_load_lds instructions stage 4 arrays x 256 rows x 16B
// into LDS slot G&3. Each instruction covers 16 rows x 64B FULL lines ->
// no reliance on cache residency. Ring depth 4 => 48 loads (48KB) in flight,
// ordered purely by in-order vmcnt: s_waitcnt vmcnt(48) per phase.
//
// LDS swizzle (both-sides, rule #21): sigma(u) = u ^ ((u>>3)&7) on f4 units
// within each 4KB slot. Applied by pre-swizzling the per-lane GLOBAL source
// row (DMA dest stays linear) and applying sigma on the ds_read index.
// sigma is an involution; it permutes within 128B so each DMA instruction's
// 1KB window is preserved; reads become bank-even (8 lanes per 4-bank group).
//
// Outputs: accumulate 16 cols per row in regs, store 64B-contiguous per row
// once per 4 phases (fixes round 2's 3x write amplification).

#define HH 256
#define WW 256
#define NG 64  // f4 col-groups along W

#define EL(v, k) ((k) == 0 ? (v).x : ((k) == 1 ? (v).y : ((k) == 2 ? (v).z : (v).w)))
#define SETEL(v, k, val)                                                     \
    do {                                                                     \
        if ((k) == 0) (v).x = (val);                                         \
        else if ((k) == 1) (v).y = (val);                                    \
        else if ((k) == 2) (v).z = (val);                                    \
        else (v).w = (val);                                                  \
    } while (0)

extern "C" __global__ void __launch_bounds__(64, 1)
spn_lr_ring(const float* __restrict__ xg, const float* __restrict__ g1g,
            const float* __restrict__ g2g, const float* __restrict__ g3g,
            float* __restrict__ outg) {
    // 4 arrays x 4 slots x 256 rows (one float4 each) = 4096 f4 = 64 KB
    __shared__ float4 smem[4096];

    const int lane = threadIdx.x;                 // 0..63
    const int wkey = (lane >> 3) & 7;             // write-side sigma key
    const int mrow = lane ^ wkey;                 // permuted row-in-64 for DMA source
    const int rkey = (lane >> 1) & 7;             // read-side sigma key ((4l+q)>>3 == l>>1)
    const size_t plane_f = (size_t)blockIdx.x * (size_t)(HH * WW);

    const float* gx = xg + plane_f;
    const float* gp1 = g1g + plane_f;
    const float* gp2 = g2g + plane_f;
    const float* gp3 = g3g + plane_f;
    float4* po = reinterpret_cast<float4*>(outg + plane_f);

    float4 bufA[4][4];  // [array][q] current/next group data (static idx only)
    float4 bufB[4][4];
    float4 o[4][4];     // [q][c4] output accum for current 16-col chunk
    float h0 = 0.0f, h1 = 0.0f, h2 = 0.0f, h3 = 0.0f;

    // ---- stage group Gf (4 arrays x 4 instr, 16 rows x 64B full lines each) ----
#define REFILL(GF)                                                              \
    do {                                                                        \
        const int slot_ = (GF) & 3;                                             \
        _Pragma("unroll") for (int a_ = 0; a_ < 4; ++a_) {                      \
            const float* base_ = (a_ == 0 ? gx : a_ == 1 ? gp1                  \
                                           : a_ == 2 ? gp2 : gp3);              \
            const float* gp_ = base_ + (size_t)mrow * WW + (GF) * 4;            \
            _Pragma("unroll") for (int i_ = 0; i_ < 4; ++i_) {                  \
                __builtin_amdgcn_global_load_lds(                               \
                    (const __attribute__((address_space(1))) void*)(gp_ + i_ * 64 * WW), \
                    (__attribute__((address_space(3))) void*)(&smem[a_ * 1024 + slot_ * 256 + i_ * 64]), \
                    16, 0, 0);                                                  \
            }                                                                   \
        }                                                                       \
    } while (0)

    // ---- ds_read group GN into BUF (sigma-swizzled, bank-even) ----
#define READS(GN, BUF)                                                          \
    do {                                                                        \
        const int slot_ = (GN) & 3;                                             \
        _Pragma("unroll") for (int a_ = 0; a_ < 4; ++a_) {                      \
            _Pragma("unroll") for (int q_ = 0; q_ < 4; ++q_) {                  \
                const int u_ = (4 * lane + q_) ^ rkey;                          \
                BUF[a_][q_] = smem[a_ * 1024 + slot_ * 256 + u_];               \
            }                                                                   \
        }                                                                       \
    } while (0)

    // ---- normalize gates in place; BUF[0] becomes d = (1-c1-c2-c3)*x ----
#define NORMALIZE(BUF)                                                          \
    do {                                                                        \
        _Pragma("unroll") for (int q_ = 0; q_ < 4; ++q_) {                      \
            _Pragma("unroll") for (int k_ = 0; k_ < 4; ++k_) {                  \
                float A1 = EL(BUF[1][q_], k_);                                  \
                float A2 = EL(BUF[2][q_], k_);                                  \
                float A3 = EL(BUF[3][q_], k_);                                  \
                const float sa = fabsf(A1) + fabsf(A2) + fabsf(A3);             \
                const float inv = (sa >= 1.0f) ? (1.0f / sa) : 1.0f;            \
                A1 *= inv; A2 *= inv; A3 *= inv;                                \
                const float d_ = (1.0f - A1 - A2 - A3) * EL(BUF[0][q_], k_);    \
                SETEL(BUF[0][q_], k_, d_);                                      \
                SETEL(BUF[1][q_], k_, A1);                                      \
                SETEL(BUF[2][q_], k_, A2);                                      \
                SETEL(BUF[3][q_], k_, A3);                                      \
            }                                                                   \
        }                                                                       \
    } while (0)

    // ---- 4 recurrence steps from BUF; fill o[*][C4] (C4 literal!) ----
#define STEPS(BUF, C4)                                                          \
    do {                                                                        \
        _Pragma("unroll") for (int k_ = 0; k_ < 4; ++k_) {                      \
            float up_ = __shfl_up(h3, 1);                                       \
            float dn_ = __shfl_down(h0, 1);                                     \
            if (lane == 0) up_ = 0.0f;                                          \
            if (lane == 63) dn_ = 0.0f;                                         \
            const float n0 = fmaf(EL(BUF[1][0], k_), up_,                       \
                             fmaf(EL(BUF[2][0], k_), h0,                        \
                             fmaf(EL(BUF[3][0], k_), h1, EL(BUF[0][0], k_))));  \
            const float n1 = fmaf(EL(BUF[1][1], k_), h0,                        \
                             fmaf(EL(BUF[2][1], k_), h1,                        \
                             fmaf(EL(BUF[3][1], k_), h2, EL(BUF[0][1], k_))));  \
            const float n2 = fmaf(EL(BUF[1][2], k_), h1,                        \
                             fmaf(EL(BUF[2][2], k_), h2,                        \
                             fmaf(EL(BUF[3][2], k_), h3, EL(BUF[0][2], k_))));  \
            const float n3 = fmaf(EL(BUF[1][3], k_), h2,                        \
                             fmaf(EL(BUF[2][3], k_), h3,                        \
                             fmaf(EL(BUF[3][3], k_), dn_, EL(BUF[0][3], k_)))); \
            h0 = n0; h1 = n1; h2 = n2; h3 = n3;                                 \
            SETEL(o[0][C4], k_, n0);                                            \
            SETEL(o[1][C4], k_, n1);                                            \
            SETEL(o[2][C4], k_, n2);                                            \
            SETEL(o[3][C4], k_, n3);                                            \
        }                                                                       \
    } while (0)

    // ---- store one 16-col chunk: 4 rows x 64B contiguous ----
#define STORECHUNK(CH)                                                          \
    do {                                                                        \
        _Pragma("unroll") for (int q_ = 0; q_ < 4; ++q_) {                      \
            _Pragma("unroll") for (int c_ = 0; c_ < 4; ++c_) {                  \
                po[(4 * lane + q_) * (WW / 4) + (CH) * 4 + c_] = o[q_][c_];     \
            }                                                                   \
        }                                                                       \
    } while (0)

    // Phase order matters:
    //  NORMALIZE first (its register uses force the compiler's lgkm waits, so
    //  all ds_reads of this slot retire before REFILL may overwrite it);
    //  then REFILL(G+4); then counted vmcnt guaranteeing refill(G+1) complete
    //  (<=48 outstanding and in-order retirement); then STEPS; then ds_reads
    //  of G+1; stores last (keeps vmcnt bookkeeping: stores are newest).
#define PHASE(G, C4, BUFC, BUFN, VMSTR, DOREFILL, DOREAD, DOSTORE)              \
    do {                                                                        \
        NORMALIZE(BUFC);                                                        \
        if (DOREFILL) REFILL((G) + 4);                                          \
        asm volatile(VMSTR ::: "memory");                                       \
        STEPS(BUFC, C4);                                                        \
        if (DOREAD) READS((G) + 1, BUFN);                                       \
        if (DOSTORE) STORECHUNK((G) >> 2);                                      \
    } while (0)

    // ---- prologue: stage groups 0..3, wait for group 0, read it ----
    REFILL(0);
    REFILL(1);
    REFILL(2);
    REFILL(3);
    asm volatile("s_waitcnt vmcnt(48)" ::: "memory");
    READS(0, bufA);

    // ---- main loop: phases G=0..59 (refills G+4 <= 63 always valid) ----
#pragma unroll 1
    for (int t = 0; t < 15; ++t) {
        const int G = t * 4;
        PHASE(G + 0, 0, bufA, bufB, "s_waitcnt vmcnt(48)", true, true, false);
        PHASE(G + 1, 1, bufB, bufA, "s_waitcnt vmcnt(48)", true, true, false);
        PHASE(G + 2, 2, bufA, bufB, "s_waitcnt vmcnt(48)", true, true, false);
        PHASE(G + 3, 3, bufB, bufA, "s_waitcnt vmcnt(48)", true, true, true);
    }

    // ---- epilogue: G=60..63, graduated vmcnt, no more refills ----
    PHASE(60, 0, bufA, bufB, "s_waitcnt vmcnt(48)", false, true, false);
    PHASE(61, 1, bufB, bufA, "s_waitcnt vmcnt(32)", false, true, false);
    PHASE(62, 2, bufA, bufB, "s_waitcnt vmcnt(16)", false, true, false);
    PHASE(63, 3, bufB, bufA, "", false, false, true);

#undef PHASE
#undef STORECHUNK
#undef STEPS
#undef NORMALIZE
#undef READS
#undef REFILL
}

extern "C" void kernel_launch(void* const* d_in, const int* in_sizes, int n_in,
                              void* d_out, int out_size, void* d_ws, size_t ws_size,
                              hipStream_t stream) {
    const float* x  = (const float*)d_in[0];
    const float* G1 = (const float*)d_in[1];
    const float* G2 = (const float*)d_in[2];
    const float* G3 = (const float*)d_in[3];
    float* out = (float*)d_out;

    const int nplanes = in_sizes[0] / (HH * WW);  // B*C = 256
    spn_lr_ring<<<dim3(nplanes), dim3(64), 0, stream>>>(x, G1, G2, G3, out);
}

// Round 4
// 192.435 us; speedup vs baseline: 1.6111x; 1.2088x over previous
//
#include <hip/hip_runtime.h>

// SPN left-to-right propagation — pure-register single-wave formulation.
//
// h[:,:,i,t] = (1-g1-g2-g3)*x[...,i,t] + g1*h[i-1,t-1] + g2*h[i,t-1] + g3*h[i+1,t-1]
// Gate normalization: if |G1|+|G2|+|G3| >= 1, divide all three by the sum.
// (sa==0 => sa<1 => keep raw, so the reference's EPS branch is dead code.)
//
// Mapping: grid=256 (one (b,c) plane per block), block=64 = ONE wave.
// Lane l owns rows 4l..4l+3. Cross-row coupling is only through h:
//   up(row 4l)   = lane l-1's h3  (__shfl_up)
//   dn(row 4l+3) = lane l+1's h0  (__shfl_down)
// All coefficients are own-row data -> NO LDS, NO barriers, NO global_load_lds
// (round 3 showed the compiler drains vmcnt(0) before ds_reads after DMA,
// serializing a single-wave pipeline; plain loads get precise counted waits).
//
// Memory discipline (fix for rounds 2/3): every 64B line is consumed entirely
// by the lane that fetches it, the phase it's fetched for. Lane holds its
// 4 rows x 16 cols x 4 arrays = 256 VGPRs of staging, refilled a 4-col
// quarter at a time right after that quarter's registers die; each quarter's
// loads are issued ~12 steps (~1500 cy) before first use -> HBM latency
// covered. Stores: 4 consecutive dwordx4 per row per phase = full 64B lines.
//
// VGPR budget: 256 staging + 64 out + ~40 working ~ 360-420 of the ~450
// usable at 1 wave/SIMD.

#define HH 256
#define WW 256

#define EL(v, k) ((k) == 0 ? (v).x : ((k) == 1 ? (v).y : ((k) == 2 ? (v).z : (v).w)))
#define SETEL(v, k, val)                                                     \
    do {                                                                     \
        if ((k) == 0) (v).x = (val);                                         \
        else if ((k) == 1) (v).y = (val);                                    \
        else if ((k) == 2) (v).z = (val);                                    \
        else (v).w = (val);                                                  \
    } while (0)

extern "C" __global__ void __launch_bounds__(64, 1)
spn_lr_reg(const float* __restrict__ xg, const float* __restrict__ g1g,
           const float* __restrict__ g2g, const float* __restrict__ g3g,
           float* __restrict__ outg) {
    const int lane = threadIdx.x;  // 0..63, owns rows 4*lane .. 4*lane+3
    const size_t off =
        (size_t)blockIdx.x * (size_t)(HH * WW) + (size_t)(4 * lane) * WW;
    const float* bx = xg + off;
    const float* b1 = g1g + off;
    const float* b2 = g2g + off;
    const float* b3 = g3g + off;
    float* bo = outg + off;

    // Staging: [row][c4-quarter] float4 per array. All indices compile-time.
    float4 Sx[4][4], S1[4][4], S2[4][4], S3[4][4];
    float4 o[4][4];  // output accumulator [row][c4]

    // ---- prologue: load group 0 (16 cols) entirely ----
#pragma unroll
    for (int r = 0; r < 4; ++r) {
#pragma unroll
        for (int c = 0; c < 4; ++c) {
            Sx[r][c] = *reinterpret_cast<const float4*>(bx + r * WW + c * 4);
            S1[r][c] = *reinterpret_cast<const float4*>(b1 + r * WW + c * 4);
            S2[r][c] = *reinterpret_cast<const float4*>(b2 + r * WW + c * 4);
            S3[r][c] = *reinterpret_cast<const float4*>(b3 + r * WW + c * 4);
        }
    }

    float h0 = 0.0f, h1 = 0.0f, h2 = 0.0f, h3 = 0.0f;

    // One recurrence step consuming element K of quarter C4.
    // Row r's coefficients normalized on the fly; n_r via fma chain.
#define ROWC(RA, HU, HC, HD, NV, C4, K)                                       \
    do {                                                                      \
        float A1 = EL(S1[RA][C4], K);                                         \
        float A2 = EL(S2[RA][C4], K);                                         \
        float A3 = EL(S3[RA][C4], K);                                         \
        const float sa = fabsf(A1) + fabsf(A2) + fabsf(A3);                   \
        const float inv = (sa >= 1.0f) ? (1.0f / sa) : 1.0f;                  \
        A1 *= inv; A2 *= inv; A3 *= inv;                                      \
        const float d = (1.0f - A1 - A2 - A3) * EL(Sx[RA][C4], K);            \
        NV = fmaf(A1, HU, fmaf(A2, HC, fmaf(A3, HD, d)));                     \
    } while (0)

#define STEP(C4, K)                                                           \
    do {                                                                      \
        float up = __shfl_up(h3, 1);                                          \
        float dn = __shfl_down(h0, 1);                                        \
        if (lane == 0) up = 0.0f;                                             \
        if (lane == 63) dn = 0.0f;                                            \
        float n0, n1, n2, n3;                                                 \
        ROWC(0, up, h0, h1, n0, C4, K);                                       \
        ROWC(1, h0, h1, h2, n1, C4, K);                                       \
        ROWC(2, h1, h2, h3, n2, C4, K);                                       \
        ROWC(3, h2, h3, dn, n3, C4, K);                                       \
        h0 = n0; h1 = n1; h2 = n2; h3 = n3;                                   \
        SETEL(o[0][C4], K, n0);                                               \
        SETEL(o[1][C4], K, n1);                                               \
        SETEL(o[2][C4], K, n2);                                               \
        SETEL(o[3][C4], K, n3);                                               \
    } while (0)

#define QUARTER(C4)                                                           \
    do { STEP(C4, 0); STEP(C4, 1); STEP(C4, 2); STEP(C4, 3); } while (0)

    // Refill quarter C4 with NEXT group's data (base + 16 cols). Issued right
    // after QUARTER(C4) killed those registers; first use is next phase's
    // QUARTER(C4), ~3 quarters (~1700 cy) away -> latency covered.
#define LOADQ(C4)                                                             \
    do {                                                                      \
        if (pre) {                                                            \
            _Pragma("unroll") for (int r_ = 0; r_ < 4; ++r_) {                \
                Sx[r_][C4] = *reinterpret_cast<const float4*>(                \
                    bx + 16 + r_ * WW + (C4) * 4);                            \
                S1[r_][C4] = *reinterpret_cast<const float4*>(                \
                    b1 + 16 + r_ * WW + (C4) * 4);                            \
                S2[r_][C4] = *reinterpret_cast<const float4*>(                \
                    b2 + 16 + r_ * WW + (C4) * 4);                            \
                S3[r_][C4] = *reinterpret_cast<const float4*>(                \
                    b3 + 16 + r_ * WW + (C4) * 4);                            \
            }                                                                 \
        }                                                                     \
    } while (0)

#pragma unroll 1
    for (int p = 0; p < 16; ++p) {
        const bool pre = (p < 15);
        QUARTER(0); LOADQ(0);
        QUARTER(1); LOADQ(1);
        QUARTER(2); LOADQ(2);
        QUARTER(3); LOADQ(3);
        // Store this phase: per row, 4 consecutive float4 = one full 64B line.
#pragma unroll
        for (int r = 0; r < 4; ++r) {
#pragma unroll
            for (int c = 0; c < 4; ++c) {
                *reinterpret_cast<float4*>(bo + r * WW + c * 4) = o[r][c];
            }
        }
        bx += 16; b1 += 16; b2 += 16; b3 += 16; bo += 16;
    }

#undef LOADQ
#undef QUARTER
#undef STEP
#undef ROWC
}

extern "C" void kernel_launch(void* const* d_in, const int* in_sizes, int n_in,
                              void* d_out, int out_size, void* d_ws, size_t ws_size,
                              hipStream_t stream) {
    const float* x  = (const float*)d_in[0];
    const float* G1 = (const float*)d_in[1];
    const float* G2 = (const float*)d_in[2];
    const float* G3 = (const float*)d_in[3];
    float* out = (float*)d_out;

    const int nplanes = in_sizes[0] / (HH * WW);  // B*C = 256
    spn_lr_reg<<<dim3(nplanes), dim3(64), 0, stream>>>(x, G1, G2, G3, out);
}